// Round 7
// baseline (6762.037 us; speedup 1.0000x reference)
//
#include <hip/hip_runtime.h>
#include <hip/hip_bf16.h>

#define TOT85 1722695ULL  // 85 * 20267

using short8 = __attribute__((ext_vector_type(8))) short;
using f32x4  = __attribute__((ext_vector_type(4))) float;

__device__ __forceinline__ float bfbits2f(short u) {
  return __uint_as_float(((unsigned int)(unsigned short)u) << 16);
}
__device__ __forceinline__ short f2bfbits(float f) {
  __hip_bfloat16 h = __float2bfloat16(f);
  return *reinterpret_cast<short*>(&h);
}

// repack conv weight [O][256][3][3] f32 -> [tap*8+chunk][NOCP oc][32 ic] bf16
// (weights consumed straight from global/L2; stride-32 rows = coalesced 1KB fragments)
__global__ __launch_bounds__(256) void repack_k(const float* __restrict__ src,
                                                __hip_bfloat16* __restrict__ dst,
                                                int O, int NOCP, int ocoff) {
  int idx = blockIdx.x * 256 + threadIdx.x;
  if (idx >= O * 2304) return;
  int o = idx / 2304;
  int r = idx - o * 2304;
  int i = r / 9;       // ic 0..255
  int t = r - i * 9;   // tap 0..8
  dst[((size_t)(t * 8 + (i >> 5)) * NOCP + (o + ocoff)) * 32 + (i & 31)] =
      __float2bfloat16(src[idx]);
}

__global__ void locations_k(float* __restrict__ out, int HW, int W, float s) {
  int i = blockIdx.x * 256 + threadIdx.x;
  if (i >= HW) return;
  int y = i / W, x = i - y * W;
  out[2 * i + 0] = x * s + 0.5f * s;
  out[2 * i + 1] = y * s + 0.5f * s;
}

// ---------------- tower kernel: r1-proven 2Mx2N shape + NT streaming ----------------
// Block: 256 thr = 4 waves (2M x 2N). Tile: 128 pixels (8 rows x 16 cols) x 256 ocs.
// acc[4][8] per wave; weights direct global->VGPR double-buffered one tap ahead.
// NEW vs r1: (a) all read-once traffic (input staging loads, dst stores) is
// NON-TEMPORAL so the 1.2MB weight panel stays L2-resident (r1 FETCH showed ~180MB
// of weight re-fetch from L3/HBM = the exposed-latency stall); (b) each chunk's
// first weight buffer load is hoisted above input staging to hide its latency.
template <bool NORM_IN, bool SRC_NCHW>
__global__ __launch_bounds__(256, 2) void conv_tower_k(
    const void* __restrict__ srcv, const __hip_bfloat16* __restrict__ wpk,
    const float* __restrict__ bias, const float* __restrict__ statsIn,
    const float* __restrict__ gamma, const float* __restrict__ beta, float inv_cnt,
    __hip_bfloat16* __restrict__ dst, float* __restrict__ statsOut,
    int H, int W, int nTx) {
  __shared__ __align__(16) short s_in[180 * 40];
  __shared__ float s_red[64];
  __shared__ float s_a[256], s_c[256];

  const int tid = threadIdx.x;
  const int lane = tid & 63;
  const int wave = tid >> 6;
  const int wm = wave >> 1;  // 0..1
  const int wn = wave & 1;   // 0..1
  const int tIdx = blockIdx.x;
  const int ty = tIdx / nTx, tx = tIdx - ty * nTx;
  const int x0 = tx * 16, y0 = ty * 8;
  const int b = blockIdx.z;
  const int HW = H * W;
  const int l15 = lane & 15;
  const int kg = lane >> 4;  // 0..3
  const int q8 = (tid & 3) * 8;

  if (tid < 64) s_red[tid] = 0.f;
  if (NORM_IN) {
    int g = tid >> 3;
    float s = statsIn[(b * 32 + g) * 2 + 0];
    float ss = statsIn[(b * 32 + g) * 2 + 1];
    float m = s * inv_cnt;
    float var = fmaf(-m, m, ss * inv_cnt);
    float rs = rsqrtf(var + 1e-5f);
    float avv = rs * gamma[tid];
    s_a[tid] = avv;
    s_c[tid] = fmaf(-m, avv, beta[tid]);
  }

  f32x4 acc[4][8];
#pragma unroll
  for (int m = 0; m < 4; ++m)
#pragma unroll
    for (int n = 0; n < 8; ++n) acc[m][n] = (f32x4){0.f, 0.f, 0.f, 0.f};

  // per-lane weight pointer: elem = ((tap*8+chunk)*256 + wn*128 + n*16 + l15)*32 + kg*8
  const short* wlane = (const short*)wpk + ((wn * 128 + l15) * 32 + kg * 8);
  const size_t TAPSTR = (size_t)8 * 256 * 32;

  for (int chunk = 0; chunk < 8; ++chunk) {
    const int ic0 = chunk * 32;
    __syncthreads();  // protect s_in from previous chunk's readers (orders s_a/s_c too)

    // hoisted: issue this chunk's tap-0 weight loads; latency hides under staging
    const short* wch = wlane + (size_t)chunk * 256 * 32;
    short8 bwA[8], bwB[8];
#pragma unroll
    for (int n = 0; n < 8; ++n) bwA[n] = *(const short8*)(wch + n * 512);

    if (SRC_NCHW) {
      const float* srcf = (const float*)srcv;
      const int pix = tid;
      if (pix < 180) {
        int prow = pix / 18;
        int pcol = pix - prow * 18;
        int gy = y0 + prow - 1, gx = x0 + pcol - 1;
        short8 sv[4];
        bool valid = (gy >= 0 && gy < H && gx >= 0 && gx < W);
        if (valid) {
          const float* p = srcf + (((size_t)(b * 256 + ic0)) * H + gy) * W + gx;
#pragma unroll
          for (int q = 0; q < 4; ++q)
#pragma unroll
            for (int j = 0; j < 8; ++j)
              sv[q][j] = f2bfbits(__builtin_nontemporal_load(p + (size_t)(q * 8 + j) * HW));
        } else {
#pragma unroll
          for (int q = 0; q < 4; ++q) sv[q] = (short8)0;
        }
#pragma unroll
        for (int q = 0; q < 4; ++q) *(short8*)(s_in + pix * 40 + q * 8) = sv[q];
      }
    } else {
      const __hip_bfloat16* srcb = (const __hip_bfloat16*)srcv;
      float av[8], cv[8];
#pragma unroll
      for (int j = 0; j < 8; ++j) {
        int c2 = ic0 + q8 + j;
        av[j] = s_a[c2];
        cv[j] = s_c[c2];
      }
      for (int idx = tid; idx < 720; idx += 256) {  // 180 pix x 4 quads(8ic)
        int pix = idx >> 2;
        int prow = pix / 18;
        int pcol = pix - prow * 18;
        int gy = y0 + prow - 1, gx = x0 + pcol - 1;
        short8 o8 = (short8)0;
        if (gy >= 0 && gy < H && gx >= 0 && gx < W) {
          const short* sp =
              (const short*)srcb + ((((size_t)b * H + gy) * W + gx) * 256 + ic0 + q8);
          short8 v8 = __builtin_nontemporal_load((const short8*)sp);
#pragma unroll
          for (int j = 0; j < 8; ++j)
            o8[j] = f2bfbits(fmaxf(fmaf(bfbits2f(v8[j]), av[j], cv[j]), 0.f));
        }
        *(short8*)(s_in + pix * 40 + q8) = o8;
      }
    }
    __syncthreads();

    auto tapbody = [&](int tap, short8* curw, short8* nxtw) {
      if (tap < 8) {  // prefetch next tap's weights (L2-resident thanks to NT streaming)
        const short* wt = wch + (size_t)(tap + 1) * TAPSTR;
#pragma unroll
        for (int n = 0; n < 8; ++n) nxtw[n] = *(const short8*)(wt + n * 512);
      }
      const int dy = tap / 3, dx = tap - dy * 3;
      short8 af[4];
#pragma unroll
      for (int m = 0; m < 4; ++m)
        af[m] = *(const short8*)(s_in + ((wm * 4 + m + dy) * 18 + (l15 + dx)) * 40 + kg * 8);
#pragma unroll
      for (int m = 0; m < 4; ++m)
#pragma unroll
        for (int n = 0; n < 8; ++n)
          acc[m][n] = __builtin_amdgcn_mfma_f32_16x16x32_bf16(af[m], curw[n], acc[m][n], 0, 0, 0);
    };
#pragma unroll
    for (int tap = 0; tap < 9; tap += 2) {
      tapbody(tap, bwA, bwB);
      if (tap + 1 < 9) tapbody(tap + 1, bwB, bwA);
    }
  }

  // epilogue: bias, NHWC bf16 NT store, GN stats
  const int masks[5] = {1, 2, 4, 16, 32};
#pragma unroll
  for (int n = 0; n < 8; ++n) {
    int oc_g = wn * 128 + n * 16 + l15;
    float bv = bias[oc_g];
    float lsum = 0.f, lssq = 0.f;
#pragma unroll
    for (int m = 0; m < 4; ++m) {
      int oy = y0 + wm * 4 + m;
#pragma unroll
      for (int r = 0; r < 4; ++r) {
        int ox = x0 + kg * 4 + r;
        bool valid = (oy < H) && (ox < W);
        float v = acc[m][n][r] + bv;
        if (valid) {
          __builtin_nontemporal_store(
              f2bfbits(v), (short*)dst + ((((size_t)b * H + oy) * W + ox) * 256 + oc_g));
          lsum += v;
          lssq += v * v;
        }
      }
    }
#pragma unroll
    for (int s = 0; s < 5; ++s) {
      lsum += __shfl_xor(lsum, masks[s], 64);
      lssq += __shfl_xor(lssq, masks[s], 64);
    }
    if ((lane & 55) == 0) {  // lanes 0 and 8: two 8-oc GN sub-groups
      int g2 = ((wn * 8 + n) * 2 + ((lane >> 3) & 1)) * 2;
      atomicAdd(&s_red[g2 + 0], lsum);
      atomicAdd(&s_red[g2 + 1], lssq);
    }
  }
  __syncthreads();
  if (tid < 64) atomicAdd(&statsOut[(size_t)b * 64 + tid], s_red[tid]);
}

// ---------------- head kernel (2Mx2N register path) ----------------
// OUT_MODE: 1 = d_out fp32 (logits oc<80, ctr oc==80 -> ch84);
//           2 = d_out fp32 expf(scale*v) at ch 80+oc.
template <int NREP, int OUT_MODE>
__global__ __launch_bounds__(256, 3) void conv_head_k(
    const void* __restrict__ srcv, const __hip_bfloat16* __restrict__ wpk,
    const float* __restrict__ bias, const float* __restrict__ bias2,
    const float* __restrict__ statsIn, const float* __restrict__ gamma,
    const float* __restrict__ beta, float inv_cnt,
    float* __restrict__ out, const float* __restrict__ scales, int lvl,
    int H, int W, int oc_valid, int nTx, int NOCP) {
  __shared__ __align__(16) short s_in[180 * 40];
  __shared__ float s_a[256], s_c[256];

  const int tid = threadIdx.x;
  const int lane = tid & 63;
  const int wave = tid >> 6;
  const int wm = wave >> 1;
  const int wn = wave & 1;
  const int tIdx = blockIdx.x;
  const int ty = tIdx / nTx, tx = tIdx - ty * nTx;
  const int x0 = tx * 16, y0 = ty * 8;
  const int b = blockIdx.z;
  const int HW = H * W;
  const int l15 = lane & 15;
  const int kg = lane >> 4;
  const int q8 = (tid & 3) * 8;

  {
    int g = tid >> 3;
    float s = statsIn[(b * 32 + g) * 2 + 0];
    float ss = statsIn[(b * 32 + g) * 2 + 1];
    float m = s * inv_cnt;
    float var = fmaf(-m, m, ss * inv_cnt);
    float rs = rsqrtf(var + 1e-5f);
    float avv = rs * gamma[tid];
    s_a[tid] = avv;
    s_c[tid] = fmaf(-m, avv, beta[tid]);
  }

  f32x4 acc[4][NREP];
#pragma unroll
  for (int m = 0; m < 4; ++m)
#pragma unroll
    for (int n = 0; n < NREP; ++n) acc[m][n] = (f32x4){0.f, 0.f, 0.f, 0.f};

  const short* wlane = (const short*)wpk + ((wn * NREP * 16 + l15) * 32 + kg * 8);
  const size_t TAPSTR = (size_t)8 * NOCP * 32;

  for (int chunk = 0; chunk < 8; ++chunk) {
    const int ic0 = chunk * 32;
    __syncthreads();

    const short* wch = wlane + (size_t)chunk * NOCP * 32;
    short8 bwA[NREP], bwB[NREP];
#pragma unroll
    for (int n = 0; n < NREP; ++n) bwA[n] = *(const short8*)(wch + n * 512);

    {
      const __hip_bfloat16* srcb = (const __hip_bfloat16*)srcv;
      float av[8], cv[8];
#pragma unroll
      for (int j = 0; j < 8; ++j) {
        int c2 = ic0 + q8 + j;
        av[j] = s_a[c2];
        cv[j] = s_c[c2];
      }
      for (int idx = tid; idx < 720; idx += 256) {
        int pix = idx >> 2;
        int prow = pix / 18;
        int pcol = pix - prow * 18;
        int gy = y0 + prow - 1, gx = x0 + pcol - 1;
        short8 o8 = (short8)0;
        if (gy >= 0 && gy < H && gx >= 0 && gx < W) {
          const short* sp =
              (const short*)srcb + ((((size_t)b * H + gy) * W + gx) * 256 + ic0 + q8);
          short8 v8 = __builtin_nontemporal_load((const short8*)sp);
#pragma unroll
          for (int j = 0; j < 8; ++j)
            o8[j] = f2bfbits(fmaxf(fmaf(bfbits2f(v8[j]), av[j], cv[j]), 0.f));
        }
        *(short8*)(s_in + pix * 40 + q8) = o8;
      }
    }
    __syncthreads();

    auto tapbody = [&](int tap, short8* curw, short8* nxtw) {
      if (tap < 8) {
        const short* wt = wch + (size_t)(tap + 1) * TAPSTR;
#pragma unroll
        for (int n = 0; n < NREP; ++n) nxtw[n] = *(const short8*)(wt + n * 512);
      }
      const int dy = tap / 3, dx = tap - dy * 3;
      short8 af[4];
#pragma unroll
      for (int m = 0; m < 4; ++m)
        af[m] = *(const short8*)(s_in + ((wm * 4 + m + dy) * 18 + (l15 + dx)) * 40 + kg * 8);
#pragma unroll
      for (int m = 0; m < 4; ++m)
#pragma unroll
        for (int n = 0; n < NREP; ++n)
          acc[m][n] = __builtin_amdgcn_mfma_f32_16x16x32_bf16(af[m], curw[n], acc[m][n], 0, 0, 0);
    };
#pragma unroll
    for (int tap = 0; tap < 9; tap += 2) {
      tapbody(tap, bwA, bwB);
      if (tap + 1 < 9) tapbody(tap + 1, bwB, bwA);
    }
  }

#pragma unroll
  for (int n = 0; n < NREP; ++n) {
    int oc_l = wn * NREP * 16 + n * 16 + l15;
    float bv;
    if (OUT_MODE == 1)
      bv = (oc_l < 80) ? bias[oc_l] : ((oc_l == 80) ? bias2[0] : 0.f);
    else
      bv = (oc_l < oc_valid) ? bias[oc_l] : 0.f;
#pragma unroll
    for (int m = 0; m < 4; ++m) {
      int oy = y0 + wm * 4 + m;
#pragma unroll
      for (int r = 0; r < 4; ++r) {
        int ox = x0 + kg * 4 + r;
        bool valid = (oy < H) && (ox < W) && (oc_l < oc_valid);
        float v = acc[m][n][r] + bv;
        if (valid) {
          if (OUT_MODE == 1) {
            int och = (oc_l == 80) ? 84 : oc_l;
            __builtin_nontemporal_store(
                v, out + ((size_t)b * TOT85 + (size_t)och * HW + oy * W + ox));
          } else {
            __builtin_nontemporal_store(
                expf(scales[lvl] * v),
                out + ((size_t)b * TOT85 + (size_t)(80 + oc_l) * HW + oy * W + ox));
          }
        }
      }
    }
  }
}

extern "C" void kernel_launch(void* const* d_in, const int* in_sizes, int n_in,
                              void* d_out_v, int out_size, void* d_ws, size_t ws_size,
                              hipStream_t stream) {
  (void)in_sizes; (void)n_in; (void)out_size; (void)ws_size;
  static const int HS[5] = {100, 50, 25, 13, 7};
  static const int WSd[5] = {152, 76, 38, 19, 10};
  static const int STRD[5] = {8, 16, 32, 64, 128};

  const float* feat[5];
  for (int i = 0; i < 5; ++i) feat[i] = (const float*)d_in[i];
  const float* cls_w = (const float*)d_in[5];
  const float* cls_b = (const float*)d_in[6];
  const float* cls_g = (const float*)d_in[7];
  const float* cls_bb = (const float*)d_in[8];
  const float* box_w = (const float*)d_in[9];
  const float* box_b = (const float*)d_in[10];
  const float* box_g = (const float*)d_in[11];
  const float* box_bb = (const float*)d_in[12];
  const float* logits_w = (const float*)d_in[13];
  const float* logits_b = (const float*)d_in[14];
  const float* ctr_w = (const float*)d_in[15];
  const float* ctr_b = (const float*)d_in[16];
  const float* reg_w = (const float*)d_in[17];
  const float* reg_b = (const float*)d_in[18];
  const float* scales = (const float*)d_in[19];
  float* d_out = (float*)d_out_v;

  char* wsp = (char*)d_ws;
  size_t off = 0;
  auto carve = [&](size_t bytes) -> char* {
    char* p = wsp + off;
    off += (bytes + 255) & ~(size_t)255;
    return p;
  };
  const size_t MAXE = (size_t)8 * 100 * 152 * 256;  // 31.13M elems
  __hip_bfloat16* bufA = (__hip_bfloat16*)carve(MAXE * 2);
  __hip_bfloat16* bufB = (__hip_bfloat16*)carve(MAXE * 2);
  const size_t TW = (size_t)9 * 8 * 256 * 32;  // per tower conv
  __hip_bfloat16* wpk_cls = (__hip_bfloat16*)carve(4 * TW * 2);
  __hip_bfloat16* wpk_box = (__hip_bfloat16*)carve(4 * TW * 2);
  __hip_bfloat16* wpk_clsh = (__hip_bfloat16*)carve((size_t)9 * 8 * 96 * 32 * 2);
  __hip_bfloat16* wpk_regh = (__hip_bfloat16*)carve((size_t)9 * 8 * 32 * 32 * 2);
  float* stats_all = (float*)carve((size_t)40 * 8 * 64 * 4);

  hipMemsetAsync(stats_all, 0, (size_t)40 * 8 * 64 * 4, stream);

  auto rp = [&](const float* s, __hip_bfloat16* d, int O, int NOCP, int ocoff) {
    int total = O * 2304;
    hipLaunchKernelGGL(repack_k, dim3((total + 255) / 256), dim3(256), 0, stream, s, d, O, NOCP,
                       ocoff);
  };
  for (int i = 0; i < 4; ++i) {
    rp(cls_w + (size_t)i * 256 * 2304, wpk_cls + (size_t)i * TW, 256, 256, 0);
    rp(box_w + (size_t)i * 256 * 2304, wpk_box + (size_t)i * TW, 256, 256, 0);
  }
  rp(logits_w, wpk_clsh, 80, 96, 0);
  rp(ctr_w, wpk_clsh, 1, 96, 80);
  rp(reg_w, wpk_regh, 4, 32, 0);

  size_t out_lvl_off = 0, loc_off = 0;
  const size_t OUT0 = (size_t)8 * TOT85;

  for (int l = 0; l < 5; ++l) {
    int H = HS[l], W = WSd[l], HW = H * W;
    int nTx = (W + 15) / 16, nTy = (H + 7) / 8;
    dim3 grid(nTx * nTy, 1, 8);
    dim3 blk(256);
    float inv_cnt = 1.f / (8.f * (float)HW);
    float* out_lvl = d_out + out_lvl_off;

    hipLaunchKernelGGL(locations_k, dim3((HW + 255) / 256), blk, 0, stream,
                       d_out + OUT0 + 2 * loc_off, HW, W, (float)STRD[l]);

    for (int t = 0; t < 2; ++t) {
      const __hip_bfloat16* wpkT = (t == 0) ? wpk_cls : wpk_box;
      const float* bt = (t == 0) ? cls_b : box_b;
      const float* gt = (t == 0) ? cls_g : box_g;
      const float* bbt = (t == 0) ? cls_bb : box_bb;
      float* slot = stats_all + (size_t)(l * 2 + t) * 4 * 512;  // 512 floats per conv slot

      // conv 0: NCHW f32 input, no norm, writes stats slot 0
      hipLaunchKernelGGL((conv_tower_k<false, true>), grid, blk, 0, stream,
                         (const void*)feat[l], wpkT, bt, (const float*)nullptr,
                         (const float*)nullptr, (const float*)nullptr, 0.f, bufA, slot, H, W,
                         nTx);
      __hip_bfloat16* cur = bufA;
      __hip_bfloat16* nxt = bufB;
      for (int i = 1; i < 4; ++i) {
        hipLaunchKernelGGL((conv_tower_k<true, false>), grid, blk, 0, stream,
                           (const void*)cur, wpkT + (size_t)i * TW, bt + i * 256,
                           slot + (size_t)(i - 1) * 512, gt + (i - 1) * 256,
                           bbt + (i - 1) * 256, inv_cnt, nxt, slot + (size_t)i * 512, H, W,
                           nTx);
        __hip_bfloat16* tmp = cur;
        cur = nxt;
        nxt = tmp;
      }
      if (t == 0) {
        hipLaunchKernelGGL((conv_head_k<3, 1>), grid, blk, 0, stream,
                           (const void*)cur, wpk_clsh, logits_b, ctr_b,
                           slot + (size_t)3 * 512, gt + 3 * 256, bbt + 3 * 256, inv_cnt,
                           out_lvl, scales, l, H, W, 81, nTx, 96);
      } else {
        hipLaunchKernelGGL((conv_head_k<1, 2>), grid, blk, 0, stream,
                           (const void*)cur, wpk_regh, reg_b, (const float*)nullptr,
                           slot + (size_t)3 * 512, gt + 3 * 256, bbt + 3 * 256, inv_cnt,
                           out_lvl, scales, l, H, W, 4, nTx, 32);
      }
    }
    out_lvl_off += (size_t)85 * HW;
    loc_off += HW;
  }
}

// Round 8
// 2487.709 us; speedup vs baseline: 2.7182x; 2.7182x over previous
//
#include <hip/hip_runtime.h>
#include <hip/hip_bf16.h>

#define TOT85 1722695ULL  // 85 * 20267

using short8 = __attribute__((ext_vector_type(8))) short;
using f32x4  = __attribute__((ext_vector_type(4))) float;

struct Feat5 { const float* p[5]; };

__device__ __forceinline__ float bfbits2f(short u) {
  return __uint_as_float(((unsigned int)(unsigned short)u) << 16);
}
__device__ __forceinline__ short f2bfbits(float f) {
  __hip_bfloat16 h = __float2bfloat16(f);
  return *reinterpret_cast<short*>(&h);
}

// level tables (compile-time; FEAT_SHAPES fixed)
#define LVL_TABLES                                                              \
  constexpr int kH[5] = {100, 50, 25, 13, 7};                                   \
  constexpr int kW[5] = {152, 76, 38, 19, 10};                                  \
  constexpr int kNTx[5] = {10, 5, 3, 2, 1};                                     \
  constexpr int kCumT[5] = {0, 130, 165, 177, 181};                             \
  constexpr int kCumHW[5] = {0, 15200, 19000, 19950, 20197};                    \
  constexpr float kInv[5] = {1.f / 121600.f, 1.f / 30400.f, 1.f / 7600.f,       \
                             1.f / 1976.f, 1.f / 560.f};

// repack conv weight [O][256][3][3] f32 -> [tap*8+chunk][NOCP oc][32 ic] bf16
__global__ __launch_bounds__(256) void repack_k(const float* __restrict__ src,
                                                __hip_bfloat16* __restrict__ dst,
                                                int O, int NOCP, int ocoff) {
  int idx = blockIdx.x * 256 + threadIdx.x;
  if (idx >= O * 2304) return;
  int o = idx / 2304;
  int r = idx - o * 2304;
  int i = r / 9;       // ic 0..255
  int t = r - i * 9;   // tap 0..8
  dst[((size_t)(t * 8 + (i >> 5)) * NOCP + (o + ocoff)) * 32 + (i & 31)] =
      __float2bfloat16(src[idx]);
}

// all levels in one dispatch
__global__ void locations_all_k(float* __restrict__ out) {
  LVL_TABLES
  constexpr int kStride[5] = {8, 16, 32, 64, 128};
  int i = blockIdx.x * 256 + threadIdx.x;
  if (i >= 20267) return;
  int lvl = (i >= 15200) + (i >= 19000) + (i >= 19950) + (i >= 20197);
  int local = i - kCumHW[lvl];
  int W = kW[lvl];
  float s = (float)kStride[lvl];
  int y = local / W, x = local - y * W;
  out[2 * i + 0] = x * s + 0.5f * s;
  out[2 * i + 1] = y * s + 0.5f * s;
}

// ---------------- tower kernel (r1-proven engine, level-batched grid) ----------------
// Block: 256 thr = 4 waves (2M x 2N). Tile: 128 pixels (8 rows x 16 cols) x 256 ocs.
// grid.x = 182 tiles across all 5 levels (block does table lookup); grid.z = batch.
// Weights: direct global->VGPR, double-buffered one tap ahead; 2 barriers/chunk.
// GN finalize fused (NORM_IN); stats slot base per (tower,conv) from host, +lvl*4096.
template <bool NORM_IN, bool SRC_NCHW>
__global__ __launch_bounds__(256, 2) void conv_tower_k(
    Feat5 feats, const __hip_bfloat16* __restrict__ srcb_base,
    const __hip_bfloat16* __restrict__ wpk, const float* __restrict__ bias,
    const float* __restrict__ statsInBase, const float* __restrict__ gamma,
    const float* __restrict__ beta, __hip_bfloat16* __restrict__ dstBase,
    float* __restrict__ statsOutBase) {
  LVL_TABLES
  __shared__ __align__(16) short s_in[180 * 40];
  __shared__ float s_red[64];
  __shared__ float s_a[256], s_c[256];

  const int tid = threadIdx.x;
  const int lane = tid & 63;
  const int wave = tid >> 6;
  const int wm = wave >> 1;  // 0..1
  const int wn = wave & 1;   // 0..1
  const int bx = blockIdx.x;
  const int lvl = (bx >= 130) + (bx >= 165) + (bx >= 177) + (bx >= 181);
  const int H = kH[lvl], W = kW[lvl], nTx = kNTx[lvl];
  const int tloc = bx - kCumT[lvl];
  const int ty = tloc / nTx, tx = tloc - ty * nTx;
  const int x0 = tx * 16, y0 = ty * 8;
  const int b = blockIdx.z;
  const int HW = H * W;
  const size_t lbase = (size_t)2048 * kCumHW[lvl];  // 8*256*cumHW elements
  const int l15 = lane & 15;
  const int kg = lane >> 4;  // 0..3
  const int q8 = (tid & 3) * 8;

  if (tid < 64) s_red[tid] = 0.f;
  if (NORM_IN) {
    const float* statsIn = statsInBase + (size_t)lvl * 4096;
    float inv_cnt = kInv[lvl];
    int g = tid >> 3;
    float s = statsIn[(b * 32 + g) * 2 + 0];
    float ss = statsIn[(b * 32 + g) * 2 + 1];
    float m = s * inv_cnt;
    float var = fmaf(-m, m, ss * inv_cnt);
    float rs = rsqrtf(var + 1e-5f);
    float avv = rs * gamma[tid];
    s_a[tid] = avv;
    s_c[tid] = fmaf(-m, avv, beta[tid]);
  }

  f32x4 acc[4][8];
#pragma unroll
  for (int m = 0; m < 4; ++m)
#pragma unroll
    for (int n = 0; n < 8; ++n) acc[m][n] = (f32x4){0.f, 0.f, 0.f, 0.f};

  // per-lane weight pointer: elem = ((tap*8+chunk)*256 + wn*128 + n*16 + l15)*32 + kg*8
  const short* wlane = (const short*)wpk + ((wn * 128 + l15) * 32 + kg * 8);
  const size_t TAPSTR = (size_t)8 * 256 * 32;

  for (int chunk = 0; chunk < 8; ++chunk) {
    const int ic0 = chunk * 32;
    __syncthreads();  // protect s_in from previous chunk's readers (orders s_a/s_c too)
    if (SRC_NCHW) {
      const float* srcf = feats.p[lvl];
      const int pix = tid;
      if (pix < 180) {
        int prow = pix / 18;
        int pcol = pix - prow * 18;
        int gy = y0 + prow - 1, gx = x0 + pcol - 1;
        short8 sv[4];
        bool valid = (gy >= 0 && gy < H && gx >= 0 && gx < W);
        if (valid) {
          const float* p = srcf + (((size_t)(b * 256 + ic0)) * H + gy) * W + gx;
#pragma unroll
          for (int q = 0; q < 4; ++q)
#pragma unroll
            for (int j = 0; j < 8; ++j)
              sv[q][j] = f2bfbits(p[(size_t)(q * 8 + j) * HW]);
        } else {
#pragma unroll
          for (int q = 0; q < 4; ++q) sv[q] = (short8)0;
        }
#pragma unroll
        for (int q = 0; q < 4; ++q) *(short8*)(s_in + pix * 40 + q * 8) = sv[q];
      }
    } else {
      const short* srcb = (const short*)srcb_base + lbase;
      float av[8], cv[8];
#pragma unroll
      for (int j = 0; j < 8; ++j) {
        int c2 = ic0 + q8 + j;
        av[j] = s_a[c2];
        cv[j] = s_c[c2];
      }
      for (int idx = tid; idx < 720; idx += 256) {  // 180 pix x 4 quads(8ic)
        int pix = idx >> 2;
        int prow = pix / 18;
        int pcol = pix - prow * 18;
        int gy = y0 + prow - 1, gx = x0 + pcol - 1;
        short8 o8 = (short8)0;
        if (gy >= 0 && gy < H && gx >= 0 && gx < W) {
          const short* sp = srcb + ((((size_t)b * H + gy) * W + gx) * 256 + ic0 + q8);
          short8 v8 = *(const short8*)sp;
#pragma unroll
          for (int j = 0; j < 8; ++j)
            o8[j] = f2bfbits(fmaxf(fmaf(bfbits2f(v8[j]), av[j], cv[j]), 0.f));
        }
        *(short8*)(s_in + pix * 40 + q8) = o8;
      }
    }
    __syncthreads();

    const short* wch = wlane + (size_t)chunk * 256 * 32;
    short8 bwA[8], bwB[8];
#pragma unroll
    for (int n = 0; n < 8; ++n) bwA[n] = *(const short8*)(wch + n * 512);

    auto tapbody = [&](int tap, short8* curw, short8* nxtw) {
      if (tap < 8) {  // prefetch next tap's weights (L2-resident)
        const short* wt = wch + (size_t)(tap + 1) * TAPSTR;
#pragma unroll
        for (int n = 0; n < 8; ++n) nxtw[n] = *(const short8*)(wt + n * 512);
      }
      const int dy = tap / 3, dx = tap - dy * 3;
      short8 af[4];
#pragma unroll
      for (int m = 0; m < 4; ++m)
        af[m] = *(const short8*)(s_in + ((wm * 4 + m + dy) * 18 + (l15 + dx)) * 40 + kg * 8);
#pragma unroll
      for (int m = 0; m < 4; ++m)
#pragma unroll
        for (int n = 0; n < 8; ++n)
          acc[m][n] = __builtin_amdgcn_mfma_f32_16x16x32_bf16(af[m], curw[n], acc[m][n], 0, 0, 0);
    };
#pragma unroll
    for (int tap = 0; tap < 9; tap += 2) {
      tapbody(tap, bwA, bwB);
      if (tap + 1 < 9) tapbody(tap + 1, bwB, bwA);
    }
  }

  // epilogue: bias, NHWC bf16 store, GN stats
  short* dst = (short*)dstBase + lbase;
  const int masks[5] = {1, 2, 4, 16, 32};
#pragma unroll
  for (int n = 0; n < 8; ++n) {
    int oc_g = wn * 128 + n * 16 + l15;
    float bv = bias[oc_g];
    float lsum = 0.f, lssq = 0.f;
#pragma unroll
    for (int m = 0; m < 4; ++m) {
      int oy = y0 + wm * 4 + m;
#pragma unroll
      for (int r = 0; r < 4; ++r) {
        int ox = x0 + kg * 4 + r;
        bool valid = (oy < H) && (ox < W);
        float v = acc[m][n][r] + bv;
        if (valid) {
          dst[(((size_t)b * H + oy) * W + ox) * 256 + oc_g] = f2bfbits(v);
          lsum += v;
          lssq += v * v;
        }
      }
    }
#pragma unroll
    for (int s = 0; s < 5; ++s) {
      lsum += __shfl_xor(lsum, masks[s], 64);
      lssq += __shfl_xor(lssq, masks[s], 64);
    }
    if ((lane & 55) == 0) {  // lanes 0 and 8: two 8-oc GN sub-groups
      int g2 = ((wn * 8 + n) * 2 + ((lane >> 3) & 1)) * 2;
      atomicAdd(&s_red[g2 + 0], lsum);
      atomicAdd(&s_red[g2 + 1], lssq);
    }
  }
  __syncthreads();
  float* statsOut = statsOutBase + (size_t)lvl * 4096;
  if (tid < 64) atomicAdd(&statsOut[(size_t)b * 64 + tid], s_red[tid]);
}

// ---------------- head kernel (2Mx2N register path, level-batched) ----------------
// OUT_MODE: 1 = d_out fp32 (logits oc<80, ctr oc==80 -> ch84);
//           2 = d_out fp32 expf(scale*v) at ch 80+oc.
template <int NREP, int OUT_MODE>
__global__ __launch_bounds__(256, 3) void conv_head_k(
    const __hip_bfloat16* __restrict__ srcb_base, const __hip_bfloat16* __restrict__ wpk,
    const float* __restrict__ bias, const float* __restrict__ bias2,
    const float* __restrict__ statsInBase, const float* __restrict__ gamma,
    const float* __restrict__ beta, float* __restrict__ out,
    const float* __restrict__ scales, int NOCP) {
  LVL_TABLES
  __shared__ __align__(16) short s_in[180 * 40];
  __shared__ float s_a[256], s_c[256];

  const int tid = threadIdx.x;
  const int lane = tid & 63;
  const int wave = tid >> 6;
  const int wm = wave >> 1;
  const int wn = wave & 1;
  const int bx = blockIdx.x;
  const int lvl = (bx >= 130) + (bx >= 165) + (bx >= 177) + (bx >= 181);
  const int H = kH[lvl], W = kW[lvl], nTx = kNTx[lvl];
  const int tloc = bx - kCumT[lvl];
  const int ty = tloc / nTx, tx = tloc - ty * nTx;
  const int x0 = tx * 16, y0 = ty * 8;
  const int b = blockIdx.z;
  const int HW = H * W;
  const size_t lbase = (size_t)2048 * kCumHW[lvl];
  float* out_lvl = out + (size_t)85 * kCumHW[lvl];
  const int l15 = lane & 15;
  const int kg = lane >> 4;
  const int q8 = (tid & 3) * 8;

  {
    const float* statsIn = statsInBase + (size_t)lvl * 4096;
    float inv_cnt = kInv[lvl];
    int g = tid >> 3;
    float s = statsIn[(b * 32 + g) * 2 + 0];
    float ss = statsIn[(b * 32 + g) * 2 + 1];
    float m = s * inv_cnt;
    float var = fmaf(-m, m, ss * inv_cnt);
    float rs = rsqrtf(var + 1e-5f);
    float avv = rs * gamma[tid];
    s_a[tid] = avv;
    s_c[tid] = fmaf(-m, avv, beta[tid]);
  }

  f32x4 acc[4][NREP];
#pragma unroll
  for (int m = 0; m < 4; ++m)
#pragma unroll
    for (int n = 0; n < NREP; ++n) acc[m][n] = (f32x4){0.f, 0.f, 0.f, 0.f};

  const short* wlane = (const short*)wpk + ((wn * NREP * 16 + l15) * 32 + kg * 8);
  const size_t TAPSTR = (size_t)8 * NOCP * 32;

  for (int chunk = 0; chunk < 8; ++chunk) {
    const int ic0 = chunk * 32;
    __syncthreads();
    {
      const short* srcb = (const short*)srcb_base + lbase;
      float av[8], cv[8];
#pragma unroll
      for (int j = 0; j < 8; ++j) {
        int c2 = ic0 + q8 + j;
        av[j] = s_a[c2];
        cv[j] = s_c[c2];
      }
      for (int idx = tid; idx < 720; idx += 256) {
        int pix = idx >> 2;
        int prow = pix / 18;
        int pcol = pix - prow * 18;
        int gy = y0 + prow - 1, gx = x0 + pcol - 1;
        short8 o8 = (short8)0;
        if (gy >= 0 && gy < H && gx >= 0 && gx < W) {
          const short* sp = srcb + ((((size_t)b * H + gy) * W + gx) * 256 + ic0 + q8);
          short8 v8 = *(const short8*)sp;
#pragma unroll
          for (int j = 0; j < 8; ++j)
            o8[j] = f2bfbits(fmaxf(fmaf(bfbits2f(v8[j]), av[j], cv[j]), 0.f));
        }
        *(short8*)(s_in + pix * 40 + q8) = o8;
      }
    }
    __syncthreads();

    const short* wch = wlane + (size_t)chunk * NOCP * 32;
    short8 bwA[NREP], bwB[NREP];
#pragma unroll
    for (int n = 0; n < NREP; ++n) bwA[n] = *(const short8*)(wch + n * 512);

    auto tapbody = [&](int tap, short8* curw, short8* nxtw) {
      if (tap < 8) {
        const short* wt = wch + (size_t)(tap + 1) * TAPSTR;
#pragma unroll
        for (int n = 0; n < NREP; ++n) nxtw[n] = *(const short8*)(wt + n * 512);
      }
      const int dy = tap / 3, dx = tap - dy * 3;
      short8 af[4];
#pragma unroll
      for (int m = 0; m < 4; ++m)
        af[m] = *(const short8*)(s_in + ((wm * 4 + m + dy) * 18 + (l15 + dx)) * 40 + kg * 8);
#pragma unroll
      for (int m = 0; m < 4; ++m)
#pragma unroll
        for (int n = 0; n < NREP; ++n)
          acc[m][n] = __builtin_amdgcn_mfma_f32_16x16x32_bf16(af[m], curw[n], acc[m][n], 0, 0, 0);
    };
#pragma unroll
    for (int tap = 0; tap < 9; tap += 2) {
      tapbody(tap, bwA, bwB);
      if (tap + 1 < 9) tapbody(tap + 1, bwB, bwA);
    }
  }

#pragma unroll
  for (int n = 0; n < NREP; ++n) {
    int oc_l = wn * NREP * 16 + n * 16 + l15;
    int oc_valid = (OUT_MODE == 1) ? 81 : 4;
    float bv;
    if (OUT_MODE == 1)
      bv = (oc_l < 80) ? bias[oc_l] : ((oc_l == 80) ? bias2[0] : 0.f);
    else
      bv = (oc_l < oc_valid) ? bias[oc_l] : 0.f;
#pragma unroll
    for (int m = 0; m < 4; ++m) {
      int oy = y0 + wm * 4 + m;
#pragma unroll
      for (int r = 0; r < 4; ++r) {
        int ox = x0 + kg * 4 + r;
        bool valid = (oy < H) && (ox < W) && (oc_l < oc_valid);
        float v = acc[m][n][r] + bv;
        if (valid) {
          if (OUT_MODE == 1) {
            int och = (oc_l == 80) ? 84 : oc_l;
            out_lvl[(size_t)b * TOT85 + (size_t)och * HW + oy * W + ox] = v;
          } else {
            out_lvl[(size_t)b * TOT85 + (size_t)(80 + oc_l) * HW + oy * W + ox] =
                expf(scales[lvl] * v);
          }
        }
      }
    }
  }
}

extern "C" void kernel_launch(void* const* d_in, const int* in_sizes, int n_in,
                              void* d_out_v, int out_size, void* d_ws, size_t ws_size,
                              hipStream_t stream) {
  (void)in_sizes; (void)n_in; (void)out_size; (void)ws_size;

  Feat5 feats;
  for (int i = 0; i < 5; ++i) feats.p[i] = (const float*)d_in[i];
  Feat5 featsNull;
  for (int i = 0; i < 5; ++i) featsNull.p[i] = nullptr;
  const float* cls_w = (const float*)d_in[5];
  const float* cls_b = (const float*)d_in[6];
  const float* cls_g = (const float*)d_in[7];
  const float* cls_bb = (const float*)d_in[8];
  const float* box_w = (const float*)d_in[9];
  const float* box_b = (const float*)d_in[10];
  const float* box_g = (const float*)d_in[11];
  const float* box_bb = (const float*)d_in[12];
  const float* logits_w = (const float*)d_in[13];
  const float* logits_b = (const float*)d_in[14];
  const float* ctr_w = (const float*)d_in[15];
  const float* ctr_b = (const float*)d_in[16];
  const float* reg_w = (const float*)d_in[17];
  const float* reg_b = (const float*)d_in[18];
  const float* scales = (const float*)d_in[19];
  float* d_out = (float*)d_out_v;

  char* wsp = (char*)d_ws;
  size_t off = 0;
  auto carve = [&](size_t bytes) -> char* {
    char* p = wsp + off;
    off += (bytes + 255) & ~(size_t)255;
    return p;
  };
  const size_t ALLE = (size_t)8 * 20267 * 256;  // all levels concat, NHWC elems
  __hip_bfloat16* bufA = (__hip_bfloat16*)carve(ALLE * 2);
  __hip_bfloat16* bufB = (__hip_bfloat16*)carve(ALLE * 2);
  const size_t TW = (size_t)9 * 8 * 256 * 32;  // per tower conv
  __hip_bfloat16* wpk_cls = (__hip_bfloat16*)carve(4 * TW * 2);
  __hip_bfloat16* wpk_box = (__hip_bfloat16*)carve(4 * TW * 2);
  __hip_bfloat16* wpk_clsh = (__hip_bfloat16*)carve((size_t)9 * 8 * 96 * 32 * 2);
  __hip_bfloat16* wpk_regh = (__hip_bfloat16*)carve((size_t)9 * 8 * 32 * 32 * 2);
  float* stats_all = (float*)carve((size_t)40 * 512 * 4);

  hipMemsetAsync(stats_all, 0, (size_t)40 * 512 * 4, stream);

  auto rp = [&](const float* s, __hip_bfloat16* d, int O, int NOCP, int ocoff) {
    int total = O * 2304;
    hipLaunchKernelGGL(repack_k, dim3((total + 255) / 256), dim3(256), 0, stream, s, d, O, NOCP,
                       ocoff);
  };
  for (int i = 0; i < 4; ++i) {
    rp(cls_w + (size_t)i * 256 * 2304, wpk_cls + (size_t)i * TW, 256, 256, 0);
    rp(box_w + (size_t)i * 256 * 2304, wpk_box + (size_t)i * TW, 256, 256, 0);
  }
  rp(logits_w, wpk_clsh, 80, 96, 0);
  rp(ctr_w, wpk_clsh, 1, 96, 80);
  rp(reg_w, wpk_regh, 4, 32, 0);

  const size_t OUT0 = (size_t)8 * TOT85;
  hipLaunchKernelGGL(locations_all_k, dim3(80), dim3(256), 0, stream, d_out + OUT0);

  dim3 grid(182, 1, 8);
  dim3 blk(256);

  for (int t = 0; t < 2; ++t) {
    const __hip_bfloat16* wpkT = (t == 0) ? wpk_cls : wpk_box;
    const float* bt = (t == 0) ? cls_b : box_b;
    const float* gt = (t == 0) ? cls_g : box_g;
    const float* bbt = (t == 0) ? cls_bb : box_bb;
    // stats slot(l,t,i) = ((l*2+t)*4+i)*512 = l*4096 + (t*4+i)*512; kernel adds l*4096
    auto slot = [&](int i) { return stats_all + (size_t)(t * 4 + i) * 512; };

    // conv 0: NCHW f32 input (all levels), no norm
    hipLaunchKernelGGL((conv_tower_k<false, true>), grid, blk, 0, stream, feats,
                       (const __hip_bfloat16*)nullptr, wpkT, bt, (const float*)nullptr,
                       (const float*)nullptr, (const float*)nullptr, bufA, slot(0));
    __hip_bfloat16* cur = bufA;
    __hip_bfloat16* nxt = bufB;
    for (int i = 1; i < 4; ++i) {
      hipLaunchKernelGGL((conv_tower_k<true, false>), grid, blk, 0, stream, featsNull,
                         (const __hip_bfloat16*)cur, wpkT + (size_t)i * TW, bt + i * 256,
                         slot(i - 1), gt + (i - 1) * 256, bbt + (i - 1) * 256, nxt, slot(i));
      __hip_bfloat16* tmp = cur;
      cur = nxt;
      nxt = tmp;
    }
    if (t == 0) {
      hipLaunchKernelGGL((conv_head_k<3, 1>), grid, blk, 0, stream, (const __hip_bfloat16*)cur,
                         wpk_clsh, logits_b, ctr_b, slot(3), gt + 3 * 256, bbt + 3 * 256,
                         d_out, scales, 96);
    } else {
      hipLaunchKernelGGL((conv_head_k<1, 2>), grid, blk, 0, stream, (const __hip_bfloat16*)cur,
                         wpk_regh, reg_b, (const float*)nullptr, slot(3), gt + 3 * 256,
                         bbt + 3 * 256, d_out, scales, 32);
    }
  }
}

// Round 9
// 2446.466 us; speedup vs baseline: 2.7640x; 1.0169x over previous
//
#include <hip/hip_runtime.h>
#include <hip/hip_bf16.h>

#define TOT85 1722695ULL  // 85 * 20267

using short8 = __attribute__((ext_vector_type(8))) short;
using f32x4  = __attribute__((ext_vector_type(4))) float;

struct Feat5 { const float* p[5]; };

__device__ __forceinline__ float bfbits2f(short u) {
  return __uint_as_float(((unsigned int)(unsigned short)u) << 16);
}
__device__ __forceinline__ short f2bfbits(float f) {
  __hip_bfloat16 h = __float2bfloat16(f);
  return *reinterpret_cast<short*>(&h);
}

// level tables (compile-time; FEAT_SHAPES fixed)
#define LVL_TABLES                                                              \
  constexpr int kH[5] = {100, 50, 25, 13, 7};                                   \
  constexpr int kW[5] = {152, 76, 38, 19, 10};                                  \
  constexpr int kNTx[5] = {10, 5, 3, 2, 1};                                     \
  constexpr int kCumT[5] = {0, 130, 165, 177, 181};                             \
  constexpr int kCumHW[5] = {0, 15200, 19000, 19950, 20197};                    \
  constexpr float kInv[5] = {1.f / 121600.f, 1.f / 30400.f, 1.f / 7600.f,       \
                             1.f / 1976.f, 1.f / 560.f};

// repack conv weight [O][256][3][3] f32 -> [tap*8+chunk][NOCP oc][32 ic] bf16
__global__ __launch_bounds__(256) void repack_k(const float* __restrict__ src,
                                                __hip_bfloat16* __restrict__ dst,
                                                int O, int NOCP, int ocoff) {
  int idx = blockIdx.x * 256 + threadIdx.x;
  if (idx >= O * 2304) return;
  int o = idx / 2304;
  int r = idx - o * 2304;
  int i = r / 9;       // ic 0..255
  int t = r - i * 9;   // tap 0..8
  dst[((size_t)(t * 8 + (i >> 5)) * NOCP + (o + ocoff)) * 32 + (i & 31)] =
      __float2bfloat16(src[idx]);
}

// all levels in one dispatch
__global__ void locations_all_k(float* __restrict__ out) {
  LVL_TABLES
  constexpr int kStride[5] = {8, 16, 32, 64, 128};
  int i = blockIdx.x * 256 + threadIdx.x;
  if (i >= 20267) return;
  int lvl = (i >= 15200) + (i >= 19000) + (i >= 19950) + (i >= 20197);
  int local = i - kCumHW[lvl];
  int W = kW[lvl];
  float s = (float)kStride[lvl];
  int y = local / W, x = local - y * W;
  out[2 * i + 0] = x * s + 0.5f * s;
  out[2 * i + 1] = y * s + 0.5f * s;
}

// ---------------- tower kernel (level-batched, 64-ic chunks, 2-phase staging) --------
// Block: 256 thr = 4 waves (2M x 2N). Tile: 128 pixels (8 rows x 16 cols) x 256 ocs.
// grid.x = 182 tiles across all 5 levels; grid.z = batch.
// Outer loop: 4 chunks of 64 ic; s_in [180 px][72 (64ic+pad8)] bf16 (stride 72 shorts
// = 36 dwords == 4 mod 32 -> 2-way bank aliasing, free). Inner: 18 K-steps, weights
// global->VGPR double-buffered one step ahead. 8 barriers/block (was 16).
// Staging is 2-phase (T14): phase A issues global loads to regs BEFORE the barrier
// (overlaps prev chunk's tap tail), phase B converts+writes LDS after it -> one
// latency exposure per chunk (was ~3), 4 exposures/block (was 8).
template <bool NORM_IN, bool SRC_NCHW>
__global__ __launch_bounds__(256, 2) void conv_tower_k(
    Feat5 feats, const __hip_bfloat16* __restrict__ srcb_base,
    const __hip_bfloat16* __restrict__ wpk, const float* __restrict__ bias,
    const float* __restrict__ statsInBase, const float* __restrict__ gamma,
    const float* __restrict__ beta, __hip_bfloat16* __restrict__ dstBase,
    float* __restrict__ statsOutBase) {
  LVL_TABLES
  __shared__ __align__(16) short s_in[180 * 72];
  __shared__ float s_red[64];
  __shared__ float s_a[256], s_c[256];

  const int tid = threadIdx.x;
  const int lane = tid & 63;
  const int wave = tid >> 6;
  const int wm = wave >> 1;  // 0..1
  const int wn = wave & 1;   // 0..1
  const int bx = blockIdx.x;
  const int lvl = (bx >= 130) + (bx >= 165) + (bx >= 177) + (bx >= 181);
  const int H = kH[lvl], W = kW[lvl], nTx = kNTx[lvl];
  const int tloc = bx - kCumT[lvl];
  const int ty = tloc / nTx, tx = tloc - ty * nTx;
  const int x0 = tx * 16, y0 = ty * 8;
  const int b = blockIdx.z;
  const int HW = H * W;
  const size_t lbase = (size_t)2048 * kCumHW[lvl];  // 8*256*cumHW elements
  const int l15 = lane & 15;
  const int kg = lane >> 4;   // 0..3
  const int q8x = (tid & 7) * 8;  // 8 ic-quads per 64-ic chunk

  if (tid < 64) s_red[tid] = 0.f;
  if (NORM_IN) {
    const float* statsIn = statsInBase + (size_t)lvl * 4096;
    float inv_cnt = kInv[lvl];
    int g = tid >> 3;
    float s = statsIn[(b * 32 + g) * 2 + 0];
    float ss = statsIn[(b * 32 + g) * 2 + 1];
    float m = s * inv_cnt;
    float var = fmaf(-m, m, ss * inv_cnt);
    float rs = rsqrtf(var + 1e-5f);
    float avv = rs * gamma[tid];
    s_a[tid] = avv;
    s_c[tid] = fmaf(-m, avv, beta[tid]);
  }

  f32x4 acc[4][8];
#pragma unroll
  for (int m = 0; m < 4; ++m)
#pragma unroll
    for (int n = 0; n < 8; ++n) acc[m][n] = (f32x4){0.f, 0.f, 0.f, 0.f};

  // per-lane weight pointer: elem = ((tap*8+chunk32)*256 + wn*128 + n*16 + l15)*32 + kg*8
  const short* wlane = (const short*)wpk + ((wn * 128 + l15) * 32 + kg * 8);

  // pixel geometry for this thread's staging role
  const int pixN = tid;                  // NCHW: one pixel per thread (<180)
  int prowN = pixN / 18;
  int pcolN = pixN - prowN * 18;
  const int gyN = y0 + prowN - 1, gxN = x0 + pcolN - 1;
  const bool validN = (pixN < 180) && (gyN >= 0 && gyN < H && gxN >= 0 && gxN < W);

  for (int c = 0; c < 4; ++c) {
    const int ic0 = c * 64;

    // ---- phase A: issue global loads into regs (no LDS touch -> before barrier) ----
    short8 pv[6];
    float fv[32];
    if (SRC_NCHW) {
      const float* srcf = feats.p[lvl];
      if (validN) {
        const float* p = srcf + (((size_t)(b * 256 + ic0)) * H + gyN) * W + gxN;
#pragma unroll
        for (int j = 0; j < 32; ++j) fv[j] = p[(size_t)j * HW];
      }
    } else {
      const short* srcb = (const short*)srcb_base + lbase;
#pragma unroll
      for (int r = 0; r < 6; ++r) {
        int idx = r * 256 + tid;
        pv[r] = (short8)0;
        if (idx < 1440) {  // 180 px x 8 quads
          int px = idx >> 3;
          int prow = px / 18;
          int pcol = px - prow * 18;
          int gy = y0 + prow - 1, gx = x0 + pcol - 1;
          if (gy >= 0 && gy < H && gx >= 0 && gx < W)
            pv[r] = *(const short8*)(srcb +
                                     ((((size_t)b * H + gy) * W + gx) * 256 + ic0 + q8x));
        }
      }
    }

    __syncthreads();  // prev chunk's readers done; phase-A loads in flight during wait

    // ---- phase B: convert + LDS write ----
    if (SRC_NCHW) {
      const float* srcf = feats.p[lvl];
      if (pixN < 180) {
        short8 sv[4];
        if (validN) {
#pragma unroll
          for (int q = 0; q < 4; ++q)
#pragma unroll
            for (int j = 0; j < 8; ++j) sv[q][j] = f2bfbits(fv[q * 8 + j]);
        } else {
#pragma unroll
          for (int q = 0; q < 4; ++q) sv[q] = (short8)0;
        }
#pragma unroll
        for (int q = 0; q < 4; ++q) *(short8*)(s_in + pixN * 72 + q * 8) = sv[q];
        // second half (ic 32..63): load+convert+write
        if (validN) {
          const float* p = srcf + (((size_t)(b * 256 + ic0 + 32)) * H + gyN) * W + gxN;
#pragma unroll
          for (int j = 0; j < 32; ++j) fv[j] = p[(size_t)j * HW];
#pragma unroll
          for (int q = 0; q < 4; ++q)
#pragma unroll
            for (int j = 0; j < 8; ++j) sv[q][j] = f2bfbits(fv[q * 8 + j]);
        }
#pragma unroll
        for (int q = 0; q < 4; ++q) *(short8*)(s_in + pixN * 72 + 32 + q * 8) = sv[q];
      }
    } else {
      float av[8], cv[8];
#pragma unroll
      for (int j = 0; j < 8; ++j) {
        int c2 = ic0 + q8x + j;
        av[j] = s_a[c2];
        cv[j] = s_c[c2];
      }
#pragma unroll
      for (int r = 0; r < 6; ++r) {
        int idx = r * 256 + tid;
        if (idx < 1440) {
          int px = idx >> 3;
          int prow = px / 18;
          int pcol = px - prow * 18;
          int gy = y0 + prow - 1, gx = x0 + pcol - 1;
          short8 o8 = (short8)0;
          if (gy >= 0 && gy < H && gx >= 0 && gx < W) {
#pragma unroll
            for (int j = 0; j < 8; ++j)
              o8[j] = f2bfbits(fmaxf(fmaf(bfbits2f(pv[r][j]), av[j], cv[j]), 0.f));
          }
          *(short8*)(s_in + px * 72 + q8x) = o8;
        }
      }
    }
    __syncthreads();

    // ---- 18 K-steps (9 taps x 2 sub-chunks), weights double-buffered 1 step ahead ----
    const short* wcb = wlane + (size_t)c * 2 * 8192;  // chunk32 = c*2 + sub
    short8 bwA[8], bwB[8];
#pragma unroll
    for (int n = 0; n < 8; ++n) bwA[n] = *(const short8*)(wcb + n * 512);

    auto kbody = [&](int k, short8* curw, short8* nxtw) {
      if (k < 17) {  // prefetch next K-step's weights (L2-resident)
        int kn = k + 1;
        const short* wt = wcb + ((size_t)((kn >> 1) * 8 + (kn & 1))) * 8192;
#pragma unroll
        for (int n = 0; n < 8; ++n) nxtw[n] = *(const short8*)(wt + n * 512);
      }
      const int tap = k >> 1, sub = k & 1;
      const int dy = tap / 3, dx = tap - dy * 3;
      short8 af[4];
#pragma unroll
      for (int m = 0; m < 4; ++m)
        af[m] = *(const short8*)(s_in + ((wm * 4 + m + dy) * 18 + (l15 + dx)) * 72 +
                                 sub * 32 + kg * 8);
#pragma unroll
      for (int m = 0; m < 4; ++m)
#pragma unroll
        for (int n = 0; n < 8; ++n)
          acc[m][n] = __builtin_amdgcn_mfma_f32_16x16x32_bf16(af[m], curw[n], acc[m][n], 0, 0, 0);
    };
#pragma unroll
    for (int k = 0; k < 18; k += 2) {
      kbody(k, bwA, bwB);
      kbody(k + 1, bwB, bwA);
    }
  }

  // epilogue: bias, NHWC bf16 store, GN stats
  short* dst = (short*)dstBase + lbase;
  const int masks[5] = {1, 2, 4, 16, 32};
#pragma unroll
  for (int n = 0; n < 8; ++n) {
    int oc_g = wn * 128 + n * 16 + l15;
    float bv = bias[oc_g];
    float lsum = 0.f, lssq = 0.f;
#pragma unroll
    for (int m = 0; m < 4; ++m) {
      int oy = y0 + wm * 4 + m;
#pragma unroll
      for (int r = 0; r < 4; ++r) {
        int ox = x0 + kg * 4 + r;
        bool valid = (oy < H) && (ox < W);
        float v = acc[m][n][r] + bv;
        if (valid) {
          dst[(((size_t)b * H + oy) * W + ox) * 256 + oc_g] = f2bfbits(v);
          lsum += v;
          lssq += v * v;
        }
      }
    }
#pragma unroll
    for (int s = 0; s < 5; ++s) {
      lsum += __shfl_xor(lsum, masks[s], 64);
      lssq += __shfl_xor(lssq, masks[s], 64);
    }
    if ((lane & 55) == 0) {  // lanes 0 and 8: two 8-oc GN sub-groups
      int g2 = ((wn * 8 + n) * 2 + ((lane >> 3) & 1)) * 2;
      atomicAdd(&s_red[g2 + 0], lsum);
      atomicAdd(&s_red[g2 + 1], lssq);
    }
  }
  __syncthreads();
  float* statsOut = statsOutBase + (size_t)lvl * 4096;
  if (tid < 64) atomicAdd(&statsOut[(size_t)b * 64 + tid], s_red[tid]);
}

// ---------------- head kernel (2Mx2N register path, level-batched) ----------------
// OUT_MODE: 1 = d_out fp32 (logits oc<80, ctr oc==80 -> ch84);
//           2 = d_out fp32 expf(scale*v) at ch 80+oc.
template <int NREP, int OUT_MODE>
__global__ __launch_bounds__(256, 3) void conv_head_k(
    const __hip_bfloat16* __restrict__ srcb_base, const __hip_bfloat16* __restrict__ wpk,
    const float* __restrict__ bias, const float* __restrict__ bias2,
    const float* __restrict__ statsInBase, const float* __restrict__ gamma,
    const float* __restrict__ beta, float* __restrict__ out,
    const float* __restrict__ scales, int NOCP) {
  LVL_TABLES
  __shared__ __align__(16) short s_in[180 * 40];
  __shared__ float s_a[256], s_c[256];

  const int tid = threadIdx.x;
  const int lane = tid & 63;
  const int wave = tid >> 6;
  const int wm = wave >> 1;
  const int wn = wave & 1;
  const int bx = blockIdx.x;
  const int lvl = (bx >= 130) + (bx >= 165) + (bx >= 177) + (bx >= 181);
  const int H = kH[lvl], W = kW[lvl], nTx = kNTx[lvl];
  const int tloc = bx - kCumT[lvl];
  const int ty = tloc / nTx, tx = tloc - ty * nTx;
  const int x0 = tx * 16, y0 = ty * 8;
  const int b = blockIdx.z;
  const int HW = H * W;
  const size_t lbase = (size_t)2048 * kCumHW[lvl];
  float* out_lvl = out + (size_t)85 * kCumHW[lvl];
  const int l15 = lane & 15;
  const int kg = lane >> 4;
  const int q8 = (tid & 3) * 8;

  {
    const float* statsIn = statsInBase + (size_t)lvl * 4096;
    float inv_cnt = kInv[lvl];
    int g = tid >> 3;
    float s = statsIn[(b * 32 + g) * 2 + 0];
    float ss = statsIn[(b * 32 + g) * 2 + 1];
    float m = s * inv_cnt;
    float var = fmaf(-m, m, ss * inv_cnt);
    float rs = rsqrtf(var + 1e-5f);
    float avv = rs * gamma[tid];
    s_a[tid] = avv;
    s_c[tid] = fmaf(-m, avv, beta[tid]);
  }

  f32x4 acc[4][NREP];
#pragma unroll
  for (int m = 0; m < 4; ++m)
#pragma unroll
    for (int n = 0; n < NREP; ++n) acc[m][n] = (f32x4){0.f, 0.f, 0.f, 0.f};

  const short* wlane = (const short*)wpk + ((wn * NREP * 16 + l15) * 32 + kg * 8);
  const size_t TAPSTR = (size_t)8 * NOCP * 32;

  for (int chunk = 0; chunk < 8; ++chunk) {
    const int ic0 = chunk * 32;
    __syncthreads();
    {
      const short* srcb = (const short*)srcb_base + lbase;
      float av[8], cv[8];
#pragma unroll
      for (int j = 0; j < 8; ++j) {
        int c2 = ic0 + q8 + j;
        av[j] = s_a[c2];
        cv[j] = s_c[c2];
      }
      for (int idx = tid; idx < 720; idx += 256) {
        int pix = idx >> 2;
        int prow = pix / 18;
        int pcol = pix - prow * 18;
        int gy = y0 + prow - 1, gx = x0 + pcol - 1;
        short8 o8 = (short8)0;
        if (gy >= 0 && gy < H && gx >= 0 && gx < W) {
          const short* sp = srcb + ((((size_t)b * H + gy) * W + gx) * 256 + ic0 + q8);
          short8 v8 = *(const short8*)sp;
#pragma unroll
          for (int j = 0; j < 8; ++j)
            o8[j] = f2bfbits(fmaxf(fmaf(bfbits2f(v8[j]), av[j], cv[j]), 0.f));
        }
        *(short8*)(s_in + pix * 40 + q8) = o8;
      }
    }
    __syncthreads();

    const short* wch = wlane + (size_t)chunk * NOCP * 32;
    short8 bwA[NREP], bwB[NREP];
#pragma unroll
    for (int n = 0; n < NREP; ++n) bwA[n] = *(const short8*)(wch + n * 512);

    auto tapbody = [&](int tap, short8* curw, short8* nxtw) {
      if (tap < 8) {
        const short* wt = wch + (size_t)(tap + 1) * TAPSTR;
#pragma unroll
        for (int n = 0; n < NREP; ++n) nxtw[n] = *(const short8*)(wt + n * 512);
      }
      const int dy = tap / 3, dx = tap - dy * 3;
      short8 af[4];
#pragma unroll
      for (int m = 0; m < 4; ++m)
        af[m] = *(const short8*)(s_in + ((wm * 4 + m + dy) * 18 + (l15 + dx)) * 40 + kg * 8);
#pragma unroll
      for (int m = 0; m < 4; ++m)
#pragma unroll
        for (int n = 0; n < NREP; ++n)
          acc[m][n] = __builtin_amdgcn_mfma_f32_16x16x32_bf16(af[m], curw[n], acc[m][n], 0, 0, 0);
    };
#pragma unroll
    for (int tap = 0; tap < 9; tap += 2) {
      tapbody(tap, bwA, bwB);
      if (tap + 1 < 9) tapbody(tap + 1, bwB, bwA);
    }
  }

#pragma unroll
  for (int n = 0; n < NREP; ++n) {
    int oc_l = wn * NREP * 16 + n * 16 + l15;
    int oc_valid = (OUT_MODE == 1) ? 81 : 4;
    float bv;
    if (OUT_MODE == 1)
      bv = (oc_l < 80) ? bias[oc_l] : ((oc_l == 80) ? bias2[0] : 0.f);
    else
      bv = (oc_l < oc_valid) ? bias[oc_l] : 0.f;
#pragma unroll
    for (int m = 0; m < 4; ++m) {
      int oy = y0 + wm * 4 + m;
#pragma unroll
      for (int r = 0; r < 4; ++r) {
        int ox = x0 + kg * 4 + r;
        bool valid = (oy < H) && (ox < W) && (oc_l < oc_valid);
        float v = acc[m][n][r] + bv;
        if (valid) {
          if (OUT_MODE == 1) {
            int och = (oc_l == 80) ? 84 : oc_l;
            out_lvl[(size_t)b * TOT85 + (size_t)och * HW + oy * W + ox] = v;
          } else {
            out_lvl[(size_t)b * TOT85 + (size_t)(80 + oc_l) * HW + oy * W + ox] =
                expf(scales[lvl] * v);
          }
        }
      }
    }
  }
}

extern "C" void kernel_launch(void* const* d_in, const int* in_sizes, int n_in,
                              void* d_out_v, int out_size, void* d_ws, size_t ws_size,
                              hipStream_t stream) {
  (void)in_sizes; (void)n_in; (void)out_size; (void)ws_size;

  Feat5 feats;
  for (int i = 0; i < 5; ++i) feats.p[i] = (const float*)d_in[i];
  Feat5 featsNull;
  for (int i = 0; i < 5; ++i) featsNull.p[i] = nullptr;
  const float* cls_w = (const float*)d_in[5];
  const float* cls_b = (const float*)d_in[6];
  const float* cls_g = (const float*)d_in[7];
  const float* cls_bb = (const float*)d_in[8];
  const float* box_w = (const float*)d_in[9];
  const float* box_b = (const float*)d_in[10];
  const float* box_g = (const float*)d_in[11];
  const float* box_bb = (const float*)d_in[12];
  const float* logits_w = (const float*)d_in[13];
  const float* logits_b = (const float*)d_in[14];
  const float* ctr_w = (const float*)d_in[15];
  const float* ctr_b = (const float*)d_in[16];
  const float* reg_w = (const float*)d_in[17];
  const float* reg_b = (const float*)d_in[18];
  const float* scales = (const float*)d_in[19];
  float* d_out = (float*)d_out_v;

  char* wsp = (char*)d_ws;
  size_t off = 0;
  auto carve = [&](size_t bytes) -> char* {
    char* p = wsp + off;
    off += (bytes + 255) & ~(size_t)255;
    return p;
  };
  const size_t ALLE = (size_t)8 * 20267 * 256;  // all levels concat, NHWC elems
  __hip_bfloat16* bufA = (__hip_bfloat16*)carve(ALLE * 2);
  __hip_bfloat16* bufB = (__hip_bfloat16*)carve(ALLE * 2);
  const size_t TW = (size_t)9 * 8 * 256 * 32;  // per tower conv
  __hip_bfloat16* wpk_cls = (__hip_bfloat16*)carve(4 * TW * 2);
  __hip_bfloat16* wpk_box = (__hip_bfloat16*)carve(4 * TW * 2);
  __hip_bfloat16* wpk_clsh = (__hip_bfloat16*)carve((size_t)9 * 8 * 96 * 32 * 2);
  __hip_bfloat16* wpk_regh = (__hip_bfloat16*)carve((size_t)9 * 8 * 32 * 32 * 2);
  float* stats_all = (float*)carve((size_t)40 * 512 * 4);

  hipMemsetAsync(stats_all, 0, (size_t)40 * 512 * 4, stream);

  auto rp = [&](const float* s, __hip_bfloat16* d, int O, int NOCP, int ocoff) {
    int total = O * 2304;
    hipLaunchKernelGGL(repack_k, dim3((total + 255) / 256), dim3(256), 0, stream, s, d, O, NOCP,
                       ocoff);
  };
  for (int i = 0; i < 4; ++i) {
    rp(cls_w + (size_t)i * 256 * 2304, wpk_cls + (size_t)i * TW, 256, 256, 0);
    rp(box_w + (size_t)i * 256 * 2304, wpk_box + (size_t)i * TW, 256, 256, 0);
  }
  rp(logits_w, wpk_clsh, 80, 96, 0);
  rp(ctr_w, wpk_clsh, 1, 96, 80);
  rp(reg_w, wpk_regh, 4, 32, 0);

  const size_t OUT0 = (size_t)8 * TOT85;
  hipLaunchKernelGGL(locations_all_k, dim3(80), dim3(256), 0, stream, d_out + OUT0);

  dim3 grid(182, 1, 8);
  dim3 blk(256);

  for (int t = 0; t < 2; ++t) {
    const __hip_bfloat16* wpkT = (t == 0) ? wpk_cls : wpk_box;
    const float* bt = (t == 0) ? cls_b : box_b;
    const float* gt = (t == 0) ? cls_g : box_g;
    const float* bbt = (t == 0) ? cls_bb : box_bb;
    // stats slot(l,t,i) = l*4096 + (t*4+i)*512; kernel adds l*4096
    auto slot = [&](int i) { return stats_all + (size_t)(t * 4 + i) * 512; };

    // conv 0: NCHW f32 input (all levels), no norm
    hipLaunchKernelGGL((conv_tower_k<false, true>), grid, blk, 0, stream, feats,
                       (const __hip_bfloat16*)nullptr, wpkT, bt, (const float*)nullptr,
                       (const float*)nullptr, (const float*)nullptr, bufA, slot(0));
    __hip_bfloat16* cur = bufA;
    __hip_bfloat16* nxt = bufB;
    for (int i = 1; i < 4; ++i) {
      hipLaunchKernelGGL((conv_tower_k<true, false>), grid, blk, 0, stream, featsNull,
                         (const __hip_bfloat16*)cur, wpkT + (size_t)i * TW, bt + i * 256,
                         slot(i - 1), gt + (i - 1) * 256, bbt + (i - 1) * 256, nxt, slot(i));
      __hip_bfloat16* tmp = cur;
      cur = nxt;
      nxt = tmp;
    }
    if (t == 0) {
      hipLaunchKernelGGL((conv_head_k<3, 1>), grid, blk, 0, stream, (const __hip_bfloat16*)cur,
                         wpk_clsh, logits_b, ctr_b, slot(3), gt + 3 * 256, bbt + 3 * 256,
                         d_out, scales, 96);
    } else {
      hipLaunchKernelGGL((conv_head_k<1, 2>), grid, blk, 0, stream, (const __hip_bfloat16*)cur,
                         wpk_regh, reg_b, (const float*)nullptr, slot(3), gt + 3 * 256,
                         bbt + 3 * 256, d_out, scales, 32);
    }
  }
}